// Round 1
// baseline (129.034 us; speedup 1.0000x reference)
//
#include <hip/hip_runtime.h>

#define NX   32
#define NN   1024          // N = NX*NX
#define NT   9
#define NCH  25            // 9 D + 8 L + 8 U
#define BATCH 2

// out[b, c, i, k]  (B, 25, N, N) float32
// A_t (5-point stencil + advection, Dirichlet):
//   diag        = kappa^2 + 4
//   A[n,n+1]    = -1 + m1[n]/2   (gx(n) < 31)
//   A[n,n-1]    = -1 - m1[n]/2   (gx(n) > 0)
//   A[n,n+32]   = -1 + m2[n]/2   (gy(n) < 31)
//   A[n,n-32]   = -1 - m2[n]/2   (gy(n) > 0)
// M_t = I + A_t  (t = 1..8),  w[n,t] = 1/tau[n,t]^2
//
// c = 0      : A0^T A0 + 1.05 I
// c = 1..8   : M_c^T diag(w_c) M_c  (+ w_c[i] on diag when c <= 7)
// c = 9..16  : L, t=c-8 :  L[i,k] = -w[k] * M[k,i]
// c = 17..24 : U, t=c-16:  U[i,k] = -w[i] * M[i,k]

__global__ __launch_bounds__(256)
void spde_kernel(const float* __restrict__ kappa,
                 const float* __restrict__ m,
                 const float* __restrict__ tau,
                 float* __restrict__ out) {
    const int row = blockIdx.x;            // 0 .. BATCH*NCH*NN-1
    const int tid = threadIdx.x;           // 0..255
    const int b   = row / (NCH * NN);
    const int rem = row - b * (NCH * NN);
    const int c   = rem / NN;
    const int i   = rem - c * NN;

    const int k0 = tid * 4;
    float4 v = make_float4(0.f, 0.f, 0.f, 0.f);

    // all non-zeros of row i lie in columns [i-64, i+64]
    if (k0 + 3 >= i - 64 && k0 <= i + 64) {
        const float kap  = kappa[0];
        const float kap2 = kap * kap;
        const int t = (c == 0) ? 0 : (c <= 8 ? c : (c <= 16 ? c - 8 : c - 16));
        // m[b, ch, n, t]: stride NT in n
        const float* __restrict__ m1 = m + ((size_t)(b * 2 + 0) * NN) * NT + t;
        const float* __restrict__ m2 = m + ((size_t)(b * 2 + 1) * NN) * NT + t;
        const float* __restrict__ tb = tau + ((size_t)b * NN) * NT + t;

        const float diag = ((c == 0) ? 4.0f : 5.0f) + kap2;

        // M_t[n,k] (0 if not a structural neighbor)
        auto Ment = [&](int n, int k) -> float {
            const int d  = k - n;
            const int gx = n & 31, gy = n >> 5;
            if (d == 0)              return diag;
            if (d == 1  && gx < 31)  return -1.0f + 0.5f * m1[n * NT];
            if (d == -1 && gx > 0)   return -1.0f - 0.5f * m1[n * NT];
            if (d == 32 && gy < 31)  return -1.0f + 0.5f * m2[n * NT];
            if (d == -32 && gy > 0)  return -1.0f - 0.5f * m2[n * NT];
            return 0.0f;
        };
        auto W = [&](int n) -> float {
            const float ta = tb[n * NT];
            return 1.0f / (ta * ta);
        };

        float vals[4];
#pragma unroll
        for (int q = 0; q < 4; ++q) {
            const int k = k0 + q;
            float val = 0.0f;
            if (c >= 17) {                       // U
                val = -W(i) * Ment(i, k);
            } else if (c >= 9) {                 // L
                const float e = Ment(k, i);
                val = (e != 0.0f) ? (-W(k) * e) : 0.0f;
            } else {                             // D: M^T diag(w) M
                const int gix = i & 31, giy = i >> 5;
                int nbr[5];
                int nn = 0;
                nbr[nn++] = i;
                if (gix < 31) nbr[nn++] = i + 1;
                if (gix > 0)  nbr[nn++] = i - 1;
                if (giy < 31) nbr[nn++] = i + 32;
                if (giy > 0)  nbr[nn++] = i - 32;
                float acc = 0.0f;
                for (int s = 0; s < nn; ++s) {
                    const int n = nbr[s];
                    const float Mni = Ment(n, i);
                    const float Mnk = Ment(n, k);
                    if (Mnk != 0.0f) {
                        const float wn = (c == 0) ? 1.0f : W(n);
                        acc += Mni * wn * Mnk;
                    }
                }
                if (k == i) {
                    if (c == 0)      acc += 1.05f;
                    else if (c <= 7) acc += W(i);
                }
                val = acc;
            }
            vals[q] = val;
        }
        v = make_float4(vals[0], vals[1], vals[2], vals[3]);
    }

    const size_t off = (size_t)row * NN + (size_t)k0;
    *reinterpret_cast<float4*>(out + off) = v;
}

extern "C" void kernel_launch(void* const* d_in, const int* in_sizes, int n_in,
                              void* d_out, int out_size, void* d_ws, size_t ws_size,
                              hipStream_t stream) {
    const float* kappa = (const float*)d_in[0];
    const float* m     = (const float*)d_in[1];
    // d_in[2] = H (unused)
    const float* tau   = (const float*)d_in[3];
    float* out = (float*)d_out;

    const int rows = BATCH * NCH * NN;     // 51200
    spde_kernel<<<rows, 256, 0, stream>>>(kappa, m, tau, out);
}